// Round 1
// baseline (550.209 us; speedup 1.0000x reference)
//
#include <hip/hip_runtime.h>
#include <hip/hip_bf16.h>

#define N_NODES 50000
#define N_EDGES 800000
#define IN_F 256
#define OUT_F 32
#define H1 8
#define NEG_SLOPE 0.2f

#define SCAN_BLK 512
#define SCAN_NB ((N_NODES + SCAN_BLK - 1) / SCAN_BLK)   // 98

// ---------------- CSR build ----------------

__global__ __launch_bounds__(256) void k_hist(const int* __restrict__ dst, int* __restrict__ deg) {
    int i = blockIdx.x * 256 + threadIdx.x;
    if (i < N_EDGES) atomicAdd(&deg[dst[i]], 1);
}

__global__ __launch_bounds__(SCAN_BLK) void k_scan1(const int* __restrict__ deg,
                                                    int* __restrict__ rowoff,  // inclusive scan temp
                                                    int* __restrict__ bsum) {
    __shared__ int s[SCAN_BLK];
    int i = blockIdx.x * SCAN_BLK + threadIdx.x;
    int v = (i < N_NODES) ? deg[i] : 0;
    s[threadIdx.x] = v;
    __syncthreads();
    for (int off = 1; off < SCAN_BLK; off <<= 1) {
        int t = (threadIdx.x >= off) ? s[threadIdx.x - off] : 0;
        __syncthreads();
        s[threadIdx.x] += t;
        __syncthreads();
    }
    if (i < N_NODES) rowoff[i] = s[threadIdx.x];
    if (threadIdx.x == SCAN_BLK - 1) bsum[blockIdx.x] = s[SCAN_BLK - 1];
}

__global__ __launch_bounds__(128) void k_scan2(int* __restrict__ bsum) {
    __shared__ int s[128];
    int t = threadIdx.x;
    int v = (t < SCAN_NB) ? bsum[t] : 0;
    s[t] = v;
    __syncthreads();
    for (int off = 1; off < 128; off <<= 1) {
        int x = (t >= off) ? s[t - off] : 0;
        __syncthreads();
        s[t] += x;
        __syncthreads();
    }
    if (t < SCAN_NB) bsum[t] = s[t] - v;  // exclusive
}

__global__ __launch_bounds__(SCAN_BLK) void k_scan3(const int* __restrict__ deg,
                                                    int* __restrict__ rowoff,
                                                    int* __restrict__ wp,
                                                    const int* __restrict__ bsum) {
    int i = blockIdx.x * SCAN_BLK + threadIdx.x;
    if (i < N_NODES) {
        int excl = rowoff[i] - deg[i] + bsum[blockIdx.x];
        rowoff[i] = excl;
        wp[i] = excl;
    }
    if (i == 0) rowoff[N_NODES] = N_EDGES;
}

__global__ __launch_bounds__(256) void k_scatter(const int* __restrict__ src, const int* __restrict__ dst,
                                                 int* __restrict__ wp, int* __restrict__ csr_src) {
    int i = blockIdx.x * 256 + threadIdx.x;
    if (i < N_EDGES) {
        int p = atomicAdd(&wp[dst[i]], 1);
        csr_src[p] = src[i];
    }
}

// ---------------- GEMM1: feat1 = x @ W1 (M x 256 @ 256 x 256) ----------------

__global__ __launch_bounds__(256) void k_gemm1(const float* __restrict__ A, const float* __restrict__ B,
                                               float* __restrict__ C) {
    __shared__ float As[16][128];
    __shared__ float Bs[16][64];
    const int t = threadIdx.x;
    const int bm0 = blockIdx.x * 128;
    const int bn0 = blockIdx.y * 64;
    const int tx = t & 15, ty = t >> 4;
    float acc[8][4] = {};
    for (int k0 = 0; k0 < 256; k0 += 16) {
        // A tile: 128 rows x 16 k  = 512 float4, 2 per thread
        #pragma unroll
        for (int l = 0; l < 2; ++l) {
            int f = t + l * 256;
            int row = f >> 2;
            int kq = (f & 3) * 4;
            float4 v = make_float4(0.f, 0.f, 0.f, 0.f);
            if (bm0 + row < N_NODES)
                v = *(const float4*)(A + (bm0 + row) * 256 + k0 + kq);
            As[kq + 0][row] = v.x;
            As[kq + 1][row] = v.y;
            As[kq + 2][row] = v.z;
            As[kq + 3][row] = v.w;
        }
        // B tile: 16 k x 64 cols = 256 float4, 1 per thread
        {
            int row = t >> 4;
            int cq = (t & 15) * 4;
            *(float4*)(&Bs[row][cq]) = *(const float4*)(B + (k0 + row) * 256 + bn0 + cq);
        }
        __syncthreads();
        #pragma unroll
        for (int k = 0; k < 16; ++k) {
            float a[8];
            #pragma unroll
            for (int i = 0; i < 8; ++i) a[i] = As[k][ty + 16 * i];
            float4 b = *(const float4*)(&Bs[k][tx * 4]);
            #pragma unroll
            for (int i = 0; i < 8; ++i) {
                acc[i][0] += a[i] * b.x;
                acc[i][1] += a[i] * b.y;
                acc[i][2] += a[i] * b.z;
                acc[i][3] += a[i] * b.w;
            }
        }
        __syncthreads();
    }
    #pragma unroll
    for (int i = 0; i < 8; ++i) {
        int m = bm0 + ty + 16 * i;
        if (m < N_NODES)
            *(float4*)(C + m * 256 + bn0 + tx * 4) =
                make_float4(acc[i][0], acc[i][1], acc[i][2], acc[i][3]);
    }
}

// ---------------- el1/er1: per-node per-head attention logits ----------------

__global__ __launch_bounds__(256) void k_elr1(const float* __restrict__ feat1,
                                              const float* __restrict__ al1, const float* __restrict__ ar1,
                                              float* __restrict__ el1, float* __restrict__ er1) {
    int wave = (blockIdx.x * 256 + threadIdx.x) >> 6;
    int lane = threadIdx.x & 63;
    if (wave >= N_NODES) return;
    int n = wave;
    int c0 = lane * 4;
    float4 f = *(const float4*)(feat1 + n * 256 + c0);
    float4 a = *(const float4*)(al1 + c0);
    float4 r = *(const float4*)(ar1 + c0);
    float pel = f.x * a.x + f.y * a.y + f.z * a.z + f.w * a.w;
    float per = f.x * r.x + f.y * r.y + f.z * r.z + f.w * r.w;
    #pragma unroll
    for (int off = 4; off >= 1; off >>= 1) {
        pel += __shfl_down(pel, off, 64);
        per += __shfl_down(per, off, 64);
    }
    if ((lane & 7) == 0) {
        el1[n * 8 + (lane >> 3)] = pel;
        er1[n * 8 + (lane >> 3)] = per;
    }
}

// ---------------- Layer-1 aggregation: one wave per dst node ----------------

__global__ __launch_bounds__(256) void k_agg1(const float* __restrict__ feat1,
                                              const float* __restrict__ el1, const float* __restrict__ er1,
                                              const float* __restrict__ x, const float* __restrict__ b1,
                                              const int* __restrict__ rowoff, const int* __restrict__ csr_src,
                                              float* __restrict__ y) {
    int v = (blockIdx.x * 256 + threadIdx.x) >> 6;
    int lane = threadIdx.x & 63;
    if (v >= N_NODES) return;
    int h = lane >> 3;
    float er = er1[v * 8 + h];
    int c0 = lane * 4;
    float4 acc = make_float4(0.f, 0.f, 0.f, 0.f);
    float wsum = 0.f;
    int s = rowoff[v], e = rowoff[v + 1];
    for (int j = s; j < e; ++j) {
        int u = csr_src[j];
        float t = el1[u * 8 + h] + er;
        t = t > 0.f ? t : NEG_SLOPE * t;
        float w = __expf(t);
        wsum += w;
        float4 f = *(const float4*)(feat1 + u * 256 + c0);
        acc.x += w * f.x;
        acc.y += w * f.y;
        acc.z += w * f.z;
        acc.w += w * f.w;
    }
    float inv = (e > s) ? 1.f / wsum : 0.f;
    float4 r = *(const float4*)(x + v * 256 + c0);
    float4 bb = *(const float4*)(b1 + c0);
    float4 o;
    o.x = fmaxf(acc.x * inv + r.x + bb.x, 0.f);
    o.y = fmaxf(acc.y * inv + r.y + bb.y, 0.f);
    o.z = fmaxf(acc.z * inv + r.z + bb.z, 0.f);
    o.w = fmaxf(acc.w * inv + r.w + bb.w, 0.f);
    *(float4*)(y + v * 256 + c0) = o;
}

// ---------------- GEMM2: feat2 = y @ W2, res2 = y @ resW2 (M x 256 @ 256 x 32, x2) ----------------

__global__ __launch_bounds__(256) void k_gemm2(const float* __restrict__ A, const float* __restrict__ W2,
                                               const float* __restrict__ resW2,
                                               float* __restrict__ feat2, float* __restrict__ res2) {
    __shared__ float As[16][128];
    __shared__ float Bs[16][64];
    const int t = threadIdx.x;
    const int bm0 = blockIdx.x * 128;
    const int tx = t & 15, ty = t >> 4;
    float acc[8][4] = {};
    for (int k0 = 0; k0 < 256; k0 += 16) {
        #pragma unroll
        for (int l = 0; l < 2; ++l) {
            int f = t + l * 256;
            int row = f >> 2;
            int kq = (f & 3) * 4;
            float4 v = make_float4(0.f, 0.f, 0.f, 0.f);
            if (bm0 + row < N_NODES)
                v = *(const float4*)(A + (bm0 + row) * 256 + k0 + kq);
            As[kq + 0][row] = v.x;
            As[kq + 1][row] = v.y;
            As[kq + 2][row] = v.z;
            As[kq + 3][row] = v.w;
        }
        {
            int row = t >> 4;
            int cq = (t & 15) * 4;
            float4 v;
            if (cq < 32)
                v = *(const float4*)(W2 + (k0 + row) * 32 + cq);
            else
                v = *(const float4*)(resW2 + (k0 + row) * 32 + (cq - 32));
            *(float4*)(&Bs[row][cq]) = v;
        }
        __syncthreads();
        #pragma unroll
        for (int k = 0; k < 16; ++k) {
            float a[8];
            #pragma unroll
            for (int i = 0; i < 8; ++i) a[i] = As[k][ty + 16 * i];
            float4 b = *(const float4*)(&Bs[k][tx * 4]);
            #pragma unroll
            for (int i = 0; i < 8; ++i) {
                acc[i][0] += a[i] * b.x;
                acc[i][1] += a[i] * b.y;
                acc[i][2] += a[i] * b.z;
                acc[i][3] += a[i] * b.w;
            }
        }
        __syncthreads();
    }
    int c = tx * 4;
    #pragma unroll
    for (int i = 0; i < 8; ++i) {
        int m = bm0 + ty + 16 * i;
        if (m < N_NODES) {
            float4 o = make_float4(acc[i][0], acc[i][1], acc[i][2], acc[i][3]);
            if (c < 32)
                *(float4*)(feat2 + m * 32 + c) = o;
            else
                *(float4*)(res2 + m * 32 + (c - 32)) = o;
        }
    }
}

// ---------------- el2/er2 ----------------

__global__ __launch_bounds__(256) void k_elr2(const float* __restrict__ feat2,
                                              const float* __restrict__ al2, const float* __restrict__ ar2,
                                              float* __restrict__ el2, float* __restrict__ er2) {
    int n = blockIdx.x * 256 + threadIdx.x;
    if (n >= N_NODES) return;
    float el = 0.f, er = 0.f;
    const float4* f4 = (const float4*)(feat2 + n * 32);
    #pragma unroll
    for (int q = 0; q < 8; ++q) {
        float4 f = f4[q];
        float4 a = ((const float4*)al2)[q];
        float4 r = ((const float4*)ar2)[q];
        el += f.x * a.x + f.y * a.y + f.z * a.z + f.w * a.w;
        er += f.x * r.x + f.y * r.y + f.z * r.z + f.w * r.w;
    }
    el2[n] = el;
    er2[n] = er;
}

// ---------------- Layer-2 aggregation: 32 lanes per dst node ----------------

__global__ __launch_bounds__(256) void k_agg2(const float* __restrict__ feat2,
                                              const float* __restrict__ el2, const float* __restrict__ er2,
                                              const float* __restrict__ res2, const float* __restrict__ b2,
                                              const int* __restrict__ rowoff, const int* __restrict__ csr_src,
                                              float* __restrict__ out) {
    int g = blockIdx.x * 256 + threadIdx.x;
    int v = g >> 5;
    int lane = g & 31;
    if (v >= N_NODES) return;
    float er = er2[v];
    float acc = 0.f, wsum = 0.f;
    int s = rowoff[v], e = rowoff[v + 1];
    for (int j = s; j < e; ++j) {
        int u = csr_src[j];
        float t = el2[u] + er;
        t = t > 0.f ? t : NEG_SLOPE * t;
        float w = __expf(t);
        wsum += w;
        acc += w * feat2[u * 32 + lane];
    }
    float inv = (e > s) ? 1.f / wsum : 0.f;
    out[v * 32 + lane] = acc * inv + res2[v * 32 + lane] + b2[lane];
}

// ---------------- launch ----------------

extern "C" void kernel_launch(void* const* d_in, const int* in_sizes, int n_in,
                              void* d_out, int out_size, void* d_ws, size_t ws_size,
                              hipStream_t stream) {
    const float* x     = (const float*)d_in[0];
    const int*   src   = (const int*)d_in[1];
    const int*   dst   = (const int*)d_in[2];
    const float* W1    = (const float*)d_in[3];
    const float* al1   = (const float*)d_in[4];
    const float* ar1   = (const float*)d_in[5];
    const float* b1    = (const float*)d_in[6];
    const float* W2    = (const float*)d_in[7];
    const float* al2   = (const float*)d_in[8];
    const float* ar2   = (const float*)d_in[9];
    const float* resW2 = (const float*)d_in[10];
    const float* b2    = (const float*)d_in[11];
    float* out = (float*)d_out;

    char* ws = (char*)d_ws;
    size_t off = 0;
    auto alloc = [&](size_t bytes) {
        void* p = ws + off;
        off += (bytes + 255) & ~(size_t)255;
        return p;
    };
    float* feat1  = (float*)alloc((size_t)N_NODES * 256 * 4);
    float* y      = (float*)alloc((size_t)N_NODES * 256 * 4);
    float* el1    = (float*)alloc((size_t)N_NODES * 8 * 4);
    float* er1    = (float*)alloc((size_t)N_NODES * 8 * 4);
    float* feat2  = (float*)alloc((size_t)N_NODES * 32 * 4);
    float* res2   = (float*)alloc((size_t)N_NODES * 32 * 4);
    float* el2    = (float*)alloc((size_t)N_NODES * 4);
    float* er2    = (float*)alloc((size_t)N_NODES * 4);
    int*   deg    = (int*)alloc((size_t)N_NODES * 4);
    int*   rowoff = (int*)alloc((size_t)(N_NODES + 1) * 4);
    int*   wp     = (int*)alloc((size_t)N_NODES * 4);
    int*   bsum   = (int*)alloc((size_t)SCAN_NB * 4);
    int*   csr    = (int*)alloc((size_t)N_EDGES * 4);
    (void)ws_size;

    // CSR build (per-call: inputs/ws are re-poisoned before every timed launch)
    hipMemsetAsync(deg, 0, (size_t)N_NODES * 4, stream);
    k_hist<<<(N_EDGES + 255) / 256, 256, 0, stream>>>(dst, deg);
    k_scan1<<<SCAN_NB, SCAN_BLK, 0, stream>>>(deg, rowoff, bsum);
    k_scan2<<<1, 128, 0, stream>>>(bsum);
    k_scan3<<<SCAN_NB, SCAN_BLK, 0, stream>>>(deg, rowoff, wp, bsum);
    k_scatter<<<(N_EDGES + 255) / 256, 256, 0, stream>>>(src, dst, wp, csr);

    // Layer 1
    dim3 g1((N_NODES + 127) / 128, 4);
    k_gemm1<<<g1, 256, 0, stream>>>(x, W1, feat1);
    k_elr1<<<(N_NODES * 64) / 256, 256, 0, stream>>>(feat1, al1, ar1, el1, er1);
    k_agg1<<<(N_NODES * 64) / 256, 256, 0, stream>>>(feat1, el1, er1, x, b1, rowoff, csr, y);

    // Layer 2
    dim3 g2((N_NODES + 127) / 128, 1);
    k_gemm2<<<g2, 256, 0, stream>>>(y, W2, resW2, feat2, res2);
    k_elr2<<<(N_NODES + 255) / 256, 256, 0, stream>>>(feat2, al2, ar2, el2, er2);
    k_agg2<<<(N_NODES * 32) / 256, 256, 0, stream>>>(feat2, el2, er2, res2, b2, rowoff, csr, out);
}

// Round 2
// 373.954 us; speedup vs baseline: 1.4713x; 1.4713x over previous
//
#include <hip/hip_runtime.h>
#include <hip/hip_bf16.h>

#define N_NODES 50000
#define N_EDGES 800000
#define NEG_SLOPE 0.2f

#define SCAN_BLK 512
#define SCAN_NB ((N_NODES + SCAN_BLK - 1) / SCAN_BLK)   // 98

typedef __attribute__((ext_vector_type(8))) short bf16x8;
typedef __attribute__((ext_vector_type(4))) float f32x4;

__device__ __forceinline__ unsigned short f2bf(float f) {
    unsigned u = __float_as_uint(f);
    u += 0x7FFFu + ((u >> 16) & 1u);          // RNE
    return (unsigned short)(u >> 16);
}
__device__ __forceinline__ float bf2f(unsigned short h) {
    return __uint_as_float(((unsigned)h) << 16);
}

// ---------------- CSR build ----------------

__global__ __launch_bounds__(256) void k_hist(const int* __restrict__ dst, int* __restrict__ deg) {
    int i = blockIdx.x * 256 + threadIdx.x;
    if (i < N_EDGES) atomicAdd(&deg[dst[i]], 1);
}

__global__ __launch_bounds__(SCAN_BLK) void k_scan1(const int* __restrict__ deg,
                                                    int* __restrict__ rowoff,
                                                    int* __restrict__ bsum) {
    __shared__ int s[SCAN_BLK];
    int i = blockIdx.x * SCAN_BLK + threadIdx.x;
    int v = (i < N_NODES) ? deg[i] : 0;
    s[threadIdx.x] = v;
    __syncthreads();
    for (int off = 1; off < SCAN_BLK; off <<= 1) {
        int t = (threadIdx.x >= off) ? s[threadIdx.x - off] : 0;
        __syncthreads();
        s[threadIdx.x] += t;
        __syncthreads();
    }
    if (i < N_NODES) rowoff[i] = s[threadIdx.x];
    if (threadIdx.x == SCAN_BLK - 1) bsum[blockIdx.x] = s[SCAN_BLK - 1];
}

__global__ __launch_bounds__(128) void k_scan2(int* __restrict__ bsum) {
    __shared__ int s[128];
    int t = threadIdx.x;
    int v = (t < SCAN_NB) ? bsum[t] : 0;
    s[t] = v;
    __syncthreads();
    for (int off = 1; off < 128; off <<= 1) {
        int x = (t >= off) ? s[t - off] : 0;
        __syncthreads();
        s[t] += x;
        __syncthreads();
    }
    if (t < SCAN_NB) bsum[t] = s[t] - v;  // exclusive
}

__global__ __launch_bounds__(SCAN_BLK) void k_scan3(const int* __restrict__ deg,
                                                    int* __restrict__ rowoff,
                                                    int* __restrict__ wp,
                                                    const int* __restrict__ bsum) {
    int i = blockIdx.x * SCAN_BLK + threadIdx.x;
    if (i < N_NODES) {
        int excl = rowoff[i] - deg[i] + bsum[blockIdx.x];
        rowoff[i] = excl;
        wp[i] = excl;
    }
    if (i == 0) rowoff[N_NODES] = N_EDGES;
}

__global__ __launch_bounds__(256) void k_scatter(const int* __restrict__ src, const int* __restrict__ dst,
                                                 int* __restrict__ wp, int* __restrict__ csr_src) {
    int i = blockIdx.x * 256 + threadIdx.x;
    if (i < N_EDGES) {
        int p = atomicAdd(&wp[dst[i]], 1);
        csr_src[p] = src[i];
    }
}

// ---------------- weight transpose + bf16 convert: in[K][Nn] f32 -> out[n][K] bf16 ----------------

__global__ __launch_bounds__(256) void k_trans(const float* __restrict__ in, unsigned short* __restrict__ out,
                                               int K, int Nn) {
    __shared__ unsigned short tile[32][33];
    int tx = threadIdx.x & 31, ty = threadIdx.x >> 5;  // 32 x 8
    int n0 = blockIdx.x * 32, k0 = blockIdx.y * 32;
    #pragma unroll
    for (int r = 0; r < 4; ++r) {
        int k = k0 + ty + r * 8;
        tile[ty + r * 8][tx] = f2bf(in[(size_t)k * Nn + n0 + tx]);
    }
    __syncthreads();
    #pragma unroll
    for (int r = 0; r < 4; ++r) {
        int n = ty + r * 8;
        out[(size_t)(n0 + n) * K + k0 + tx] = tile[tx][n];
    }
}

// ---------------- GEMM1 (MFMA bf16): feat1b = bf16(x) @ W1  (M x 256 @ 256 x 256) ----------------
// A staged fp32->bf16 in-register; B = W1T [n][k] bf16. LDS stride 40 shorts (pad) -> <=2-way banks.

#define LDA 40

__global__ __launch_bounds__(256) void k_gemm1(const float* __restrict__ A,
                                               const unsigned short* __restrict__ BT,
                                               unsigned short* __restrict__ Cb) {
    __shared__ unsigned short As[128 * LDA];
    __shared__ unsigned short Bs[128 * LDA];
    const int t = threadIdx.x;
    const int bm0 = blockIdx.x * 128;
    const int bn0 = blockIdx.y * 128;
    const int wave = t >> 6, lane = t & 63;
    const int wm = (wave & 1) * 64, wn = (wave >> 1) * 64;
    const int lm = lane & 15, quad = lane >> 4;

    f32x4 acc[4][4];
    #pragma unroll
    for (int i = 0; i < 4; ++i)
        #pragma unroll
        for (int j = 0; j < 4; ++j)
            #pragma unroll
            for (int r = 0; r < 4; ++r) acc[i][j][r] = 0.f;

    for (int k0 = 0; k0 < 256; k0 += 32) {
        // A tile: 128 rows x 32 f32 -> bf16. 1024 float4 chunks, 4/thread.
        #pragma unroll
        for (int l = 0; l < 4; ++l) {
            int f = t + l * 256;
            int row = f >> 3;
            int q = f & 7;
            float4 v = make_float4(0.f, 0.f, 0.f, 0.f);
            if (bm0 + row < N_NODES)
                v = *(const float4*)(A + (size_t)(bm0 + row) * 256 + k0 + q * 4);
            ushort4 h;
            h.x = f2bf(v.x); h.y = f2bf(v.y); h.z = f2bf(v.z); h.w = f2bf(v.w);
            *(ushort4*)(&As[row * LDA + q * 4]) = h;
        }
        // B tile: 128 n-rows x 32 k bf16 = 512 16B chunks, 2/thread.
        #pragma unroll
        for (int l = 0; l < 2; ++l) {
            int f = t + l * 256;
            int row = f >> 2;
            int q = f & 3;
            int4 v = *(const int4*)(BT + (size_t)(bn0 + row) * 256 + k0 + q * 8);
            *(int4*)(&Bs[row * LDA + q * 8]) = v;
        }
        __syncthreads();
        bf16x8 af[4], bfr[4];
        #pragma unroll
        for (int i = 0; i < 4; ++i)
            af[i] = *(const bf16x8*)(&As[(wm + i * 16 + lm) * LDA + quad * 8]);
        #pragma unroll
        for (int i = 0; i < 4; ++i)
            bfr[i] = *(const bf16x8*)(&Bs[(wn + i * 16 + lm) * LDA + quad * 8]);
        #pragma unroll
        for (int mi = 0; mi < 4; ++mi)
            #pragma unroll
            for (int ni = 0; ni < 4; ++ni)
                acc[mi][ni] = __builtin_amdgcn_mfma_f32_16x16x32_bf16(af[mi], bfr[ni], acc[mi][ni], 0, 0, 0);
        __syncthreads();
    }
    // epilogue: C/D layout col=lane&15, row=quad*4+r. Store bf16.
    #pragma unroll
    for (int mi = 0; mi < 4; ++mi) {
        #pragma unroll
        for (int ni = 0; ni < 4; ++ni) {
            int col = bn0 + wn + ni * 16 + lm;
            #pragma unroll
            for (int r = 0; r < 4; ++r) {
                int row = bm0 + wm + mi * 16 + quad * 4 + r;
                if (row < N_NODES)
                    Cb[(size_t)row * 256 + col] = f2bf(acc[mi][ni][r]);
            }
        }
    }
}

// ---------------- GEMM2 (MFMA bf16): [feat2|res2] = y_b @ [W2|resW2]  (M x 256 @ 256 x 64) ----------------

__global__ __launch_bounds__(256) void k_gemm2(const unsigned short* __restrict__ Ab,
                                               const unsigned short* __restrict__ BT,  // [64][256]
                                               float* __restrict__ feat2, float* __restrict__ res2) {
    __shared__ unsigned short As[128 * LDA];
    __shared__ unsigned short Bs[64 * LDA];
    const int t = threadIdx.x;
    const int bm0 = blockIdx.x * 128;
    const int wave = t >> 6, lane = t & 63;
    const int wm = (wave & 1) * 64, wn = (wave >> 1) * 32;
    const int lm = lane & 15, quad = lane >> 4;

    f32x4 acc[4][2];
    #pragma unroll
    for (int i = 0; i < 4; ++i)
        #pragma unroll
        for (int j = 0; j < 2; ++j)
            #pragma unroll
            for (int r = 0; r < 4; ++r) acc[i][j][r] = 0.f;

    for (int k0 = 0; k0 < 256; k0 += 32) {
        // A tile: 128 x 32 bf16 = 512 16B chunks, 2/thread
        #pragma unroll
        for (int l = 0; l < 2; ++l) {
            int f = t + l * 256;
            int row = f >> 2;
            int q = f & 3;
            int4 v = {0, 0, 0, 0};
            if (bm0 + row < N_NODES)
                v = *(const int4*)(Ab + (size_t)(bm0 + row) * 256 + k0 + q * 8);
            *(int4*)(&As[row * LDA + q * 8]) = v;
        }
        // B tile: 64 x 32 bf16 = 256 16B chunks, 1/thread
        {
            int row = t >> 2;
            int q = t & 3;
            int4 v = *(const int4*)(BT + (size_t)row * 256 + k0 + q * 8);
            *(int4*)(&Bs[row * LDA + q * 8]) = v;
        }
        __syncthreads();
        bf16x8 af[4], bfr[2];
        #pragma unroll
        for (int i = 0; i < 4; ++i)
            af[i] = *(const bf16x8*)(&As[(wm + i * 16 + lm) * LDA + quad * 8]);
        #pragma unroll
        for (int i = 0; i < 2; ++i)
            bfr[i] = *(const bf16x8*)(&Bs[(wn + i * 16 + lm) * LDA + quad * 8]);
        #pragma unroll
        for (int mi = 0; mi < 4; ++mi)
            #pragma unroll
            for (int ni = 0; ni < 2; ++ni)
                acc[mi][ni] = __builtin_amdgcn_mfma_f32_16x16x32_bf16(af[mi], bfr[ni], acc[mi][ni], 0, 0, 0);
        __syncthreads();
    }
    #pragma unroll
    for (int mi = 0; mi < 4; ++mi) {
        #pragma unroll
        for (int ni = 0; ni < 2; ++ni) {
            int col = wn + ni * 16 + lm;  // 0..63
            #pragma unroll
            for (int r = 0; r < 4; ++r) {
                int row = bm0 + wm + mi * 16 + quad * 4 + r;
                if (row < N_NODES) {
                    float val = acc[mi][ni][r];
                    if (col < 32) feat2[(size_t)row * 32 + col] = val;
                    else          res2[(size_t)row * 32 + col - 32] = val;
                }
            }
        }
    }
}

// ---------------- el1/er1 from bf16 feat ----------------

__global__ __launch_bounds__(256) void k_elr1(const unsigned short* __restrict__ feat1b,
                                              const float* __restrict__ al1, const float* __restrict__ ar1,
                                              float* __restrict__ el1, float* __restrict__ er1) {
    int n = (blockIdx.x * 256 + threadIdx.x) >> 6;
    int lane = threadIdx.x & 63;
    if (n >= N_NODES) return;
    int c0 = lane * 4;
    ushort4 hv = *(const ushort4*)(feat1b + (size_t)n * 256 + c0);
    float4 a = *(const float4*)(al1 + c0);
    float4 r = *(const float4*)(ar1 + c0);
    float fx = bf2f(hv.x), fy = bf2f(hv.y), fz = bf2f(hv.z), fw = bf2f(hv.w);
    float pel = fx * a.x + fy * a.y + fz * a.z + fw * a.w;
    float per = fx * r.x + fy * r.y + fz * r.z + fw * r.w;
    #pragma unroll
    for (int off = 4; off >= 1; off >>= 1) {
        pel += __shfl_down(pel, off, 64);
        per += __shfl_down(per, off, 64);
    }
    if ((lane & 7) == 0) {
        el1[n * 8 + (lane >> 3)] = pel;
        er1[n * 8 + (lane >> 3)] = per;
    }
}

// ---------------- Layer-1 aggregation: one wave per dst node, bf16 feat gather ----------------

__global__ __launch_bounds__(256) void k_agg1(const unsigned short* __restrict__ feat1b,
                                              const float* __restrict__ el1, const float* __restrict__ er1,
                                              const float* __restrict__ x, const float* __restrict__ b1,
                                              const int* __restrict__ rowoff, const int* __restrict__ csr_src,
                                              unsigned short* __restrict__ y_b) {
    int v = (blockIdx.x * 256 + threadIdx.x) >> 6;
    int lane = threadIdx.x & 63;
    if (v >= N_NODES) return;
    int h = lane >> 3;
    float er = er1[v * 8 + h];
    int c0 = lane * 4;
    float ax = 0.f, ay = 0.f, az = 0.f, aw = 0.f, wsum = 0.f;
    int s = rowoff[v], e = rowoff[v + 1];
    int j = s;
    for (; j + 1 < e; j += 2) {  // 2-wide for MLP
        int u0 = csr_src[j], u1 = csr_src[j + 1];
        float t0 = el1[u0 * 8 + h] + er;
        float t1 = el1[u1 * 8 + h] + er;
        ushort4 h0 = *(const ushort4*)(feat1b + (size_t)u0 * 256 + c0);
        ushort4 h1 = *(const ushort4*)(feat1b + (size_t)u1 * 256 + c0);
        t0 = t0 > 0.f ? t0 : NEG_SLOPE * t0;
        t1 = t1 > 0.f ? t1 : NEG_SLOPE * t1;
        float w0 = __expf(t0), w1 = __expf(t1);
        wsum += w0 + w1;
        ax += w0 * bf2f(h0.x) + w1 * bf2f(h1.x);
        ay += w0 * bf2f(h0.y) + w1 * bf2f(h1.y);
        az += w0 * bf2f(h0.z) + w1 * bf2f(h1.z);
        aw += w0 * bf2f(h0.w) + w1 * bf2f(h1.w);
    }
    if (j < e) {
        int u = csr_src[j];
        float t = el1[u * 8 + h] + er;
        ushort4 hh = *(const ushort4*)(feat1b + (size_t)u * 256 + c0);
        t = t > 0.f ? t : NEG_SLOPE * t;
        float w = __expf(t);
        wsum += w;
        ax += w * bf2f(hh.x);
        ay += w * bf2f(hh.y);
        az += w * bf2f(hh.z);
        aw += w * bf2f(hh.w);
    }
    float inv = (e > s) ? 1.f / wsum : 0.f;
    float4 r = *(const float4*)(x + (size_t)v * 256 + c0);
    float4 bb = *(const float4*)(b1 + c0);
    ushort4 o;
    o.x = f2bf(fmaxf(ax * inv + r.x + bb.x, 0.f));
    o.y = f2bf(fmaxf(ay * inv + r.y + bb.y, 0.f));
    o.z = f2bf(fmaxf(az * inv + r.z + bb.z, 0.f));
    o.w = f2bf(fmaxf(aw * inv + r.w + bb.w, 0.f));
    *(ushort4*)(y_b + (size_t)v * 256 + c0) = o;
}

// ---------------- el2/er2 ----------------

__global__ __launch_bounds__(256) void k_elr2(const float* __restrict__ feat2,
                                              const float* __restrict__ al2, const float* __restrict__ ar2,
                                              float* __restrict__ el2, float* __restrict__ er2) {
    int n = blockIdx.x * 256 + threadIdx.x;
    if (n >= N_NODES) return;
    float el = 0.f, er = 0.f;
    const float4* f4 = (const float4*)(feat2 + (size_t)n * 32);
    #pragma unroll
    for (int q = 0; q < 8; ++q) {
        float4 f = f4[q];
        float4 a = ((const float4*)al2)[q];
        float4 r = ((const float4*)ar2)[q];
        el += f.x * a.x + f.y * a.y + f.z * a.z + f.w * a.w;
        er += f.x * r.x + f.y * r.y + f.z * r.z + f.w * r.w;
    }
    el2[n] = el;
    er2[n] = er;
}

// ---------------- Layer-2 aggregation: 32 lanes per dst node ----------------

__global__ __launch_bounds__(256) void k_agg2(const float* __restrict__ feat2,
                                              const float* __restrict__ el2, const float* __restrict__ er2,
                                              const float* __restrict__ res2, const float* __restrict__ b2,
                                              const int* __restrict__ rowoff, const int* __restrict__ csr_src,
                                              float* __restrict__ out) {
    int g = blockIdx.x * 256 + threadIdx.x;
    int v = g >> 5;
    int lane = g & 31;
    if (v >= N_NODES) return;
    float er = er2[v];
    float acc = 0.f, wsum = 0.f;
    int s = rowoff[v], e = rowoff[v + 1];
    for (int j = s; j < e; ++j) {
        int u = csr_src[j];
        float t = el2[u] + er;
        t = t > 0.f ? t : NEG_SLOPE * t;
        float w = __expf(t);
        wsum += w;
        acc += w * feat2[(size_t)u * 32 + lane];
    }
    float inv = (e > s) ? 1.f / wsum : 0.f;
    out[(size_t)v * 32 + lane] = acc * inv + res2[(size_t)v * 32 + lane] + b2[lane];
}

// ---------------- launch ----------------

extern "C" void kernel_launch(void* const* d_in, const int* in_sizes, int n_in,
                              void* d_out, int out_size, void* d_ws, size_t ws_size,
                              hipStream_t stream) {
    const float* x     = (const float*)d_in[0];
    const int*   src   = (const int*)d_in[1];
    const int*   dst   = (const int*)d_in[2];
    const float* W1    = (const float*)d_in[3];
    const float* al1   = (const float*)d_in[4];
    const float* ar1   = (const float*)d_in[5];
    const float* b1    = (const float*)d_in[6];
    const float* W2    = (const float*)d_in[7];
    const float* al2   = (const float*)d_in[8];
    const float* ar2   = (const float*)d_in[9];
    const float* resW2 = (const float*)d_in[10];
    const float* b2    = (const float*)d_in[11];
    float* out = (float*)d_out;

    char* ws = (char*)d_ws;
    size_t off = 0;
    auto alloc = [&](size_t bytes) {
        void* p = ws + off;
        off += (bytes + 255) & ~(size_t)255;
        return p;
    };
    unsigned short* feat1b = (unsigned short*)alloc((size_t)N_NODES * 256 * 2);
    unsigned short* y_b    = (unsigned short*)alloc((size_t)N_NODES * 256 * 2);
    unsigned short* W1T    = (unsigned short*)alloc((size_t)256 * 256 * 2);
    unsigned short* W2T    = (unsigned short*)alloc((size_t)64 * 256 * 2);
    float* el1    = (float*)alloc((size_t)N_NODES * 8 * 4);
    float* er1    = (float*)alloc((size_t)N_NODES * 8 * 4);
    float* feat2  = (float*)alloc((size_t)N_NODES * 32 * 4);
    float* res2   = (float*)alloc((size_t)N_NODES * 32 * 4);
    float* el2    = (float*)alloc((size_t)N_NODES * 4);
    float* er2    = (float*)alloc((size_t)N_NODES * 4);
    int*   deg    = (int*)alloc((size_t)N_NODES * 4);
    int*   rowoff = (int*)alloc((size_t)(N_NODES + 1) * 4);
    int*   wp     = (int*)alloc((size_t)N_NODES * 4);
    int*   bsum   = (int*)alloc((size_t)SCAN_NB * 4);
    int*   csr    = (int*)alloc((size_t)N_EDGES * 4);
    (void)ws_size;

    // CSR build (rebuilt every call: ws is re-poisoned before each timed launch)
    hipMemsetAsync(deg, 0, (size_t)N_NODES * 4, stream);
    k_hist<<<(N_EDGES + 255) / 256, 256, 0, stream>>>(dst, deg);
    k_scan1<<<SCAN_NB, SCAN_BLK, 0, stream>>>(deg, rowoff, bsum);
    k_scan2<<<1, 128, 0, stream>>>(bsum);
    k_scan3<<<SCAN_NB, SCAN_BLK, 0, stream>>>(deg, rowoff, wp, bsum);
    k_scatter<<<(N_EDGES + 255) / 256, 256, 0, stream>>>(src, dst, wp, csr);

    // Weight transposes -> bf16 [n][k]
    k_trans<<<dim3(8, 8), 256, 0, stream>>>(W1, W1T, 256, 256);
    k_trans<<<dim3(1, 8), 256, 0, stream>>>(W2, W2T, 256, 32);
    k_trans<<<dim3(1, 8), 256, 0, stream>>>(resW2, W2T + 32 * 256, 256, 32);

    // Layer 1
    dim3 g1((N_NODES + 127) / 128, 2);
    k_gemm1<<<g1, 256, 0, stream>>>(x, W1T, feat1b);
    k_elr1<<<(N_NODES * 64) / 256, 256, 0, stream>>>(feat1b, al1, ar1, el1, er1);
    k_agg1<<<(N_NODES * 64) / 256, 256, 0, stream>>>(feat1b, el1, er1, x, b1, rowoff, csr, y_b);

    // Layer 2
    k_gemm2<<<(N_NODES + 127) / 128, 256, 0, stream>>>(y_b, W2T, feat2, res2);
    k_elr2<<<(N_NODES + 255) / 256, 256, 0, stream>>>(feat2, al2, ar2, el2, er2);
    k_agg2<<<(N_NODES * 32) / 256, 256, 0, stream>>>(feat2, el2, er2, res2, b2, rowoff, csr, out);
}